// Round 10
// baseline (136.367 us; speedup 1.0000x reference)
//
#include <hip/hip_runtime.h>

// ---------------------------------------------------------------------------
// VectorQuantizer R10: code-split scoring (R7 geometry, 4 blocks/CU) +
// straggler-free merge (R8 logic).
// R9 post-mortem: fused kernel was GRID-bound (512 blocks = 2 blocks/CU);
// counted-vmcnt was null. R7 measured this score geometry at ~25us.
//   prep  : E -> ET fp32 [1024][256], ETbf fragment-linear bf16, norms
//   score : dim3(2,512): block = 64 rows x 512 codes, 16 chunks of 32 codes,
//           2-buf LDS via global_load_lds, top-3 + escalation tracking,
//           meta (rowmin/cnt/esc/cand[8]) to global.
//   merge : per row: final thr = min(rm0,rm1)+MARGIN; filter stored keys;
//           kept==1 & no esc -> direct gather; else shuffle-parallel fp32
//           rescore + lane-parallel esc rescans; cnt>8 -> lane-parallel
//           full scan (all paths bounded ~us).
//   loss  : sum 2048 double partials.
// Exactness: true argmin c* has bf16 score <= final_min+2B < final_thr <=
// split_thr, so c* is pushed (or cnt>8 full-scan) or its lane escalated;
// all such codes rescored in exact fp32 with index tie-break. (R8-verified.)
// ---------------------------------------------------------------------------

constexpr int Mrows = 32768;
constexpr int Ddim  = 256;
constexpr int Kcode = 1024;

constexpr int   CAPG   = 8;      // stored candidates per row-split
constexpr float MARGIN = 0.25f;

typedef unsigned long long u64;
typedef unsigned short ushort_t;
typedef __attribute__((ext_vector_type(8))) short bf16x8;
typedef __attribute__((ext_vector_type(4))) float f32x4;

__device__ inline u64 packKey(float v, int idx) {
    unsigned u = __float_as_uint(v);
    u = (u & 0x80000000u) ? ~u : (u | 0x80000000u);   // order-preserving
    return ((u64)u << 32) | (unsigned)idx;
}
__device__ inline float unpackScore(u64 k) {
    unsigned v = (unsigned)(k >> 32);
    unsigned orig = (v & 0x80000000u) ? (v ^ 0x80000000u) : ~v;
    return __uint_as_float(orig);
}
__device__ inline ushort_t f2bf(float f) {   // RTN-even
    unsigned u = __float_as_uint(f);
    return (ushort_t)((u + 0x7fffu + ((u >> 16) & 1u)) >> 16);
}
__device__ inline void gload_lds16(const void* g, void* l) {
    __builtin_amdgcn_global_load_lds(
        (const __attribute__((address_space(1))) unsigned int*)g,
        (__attribute__((address_space(3))) unsigned int*)l, 16, 0, 0);
}

// ---- prep: block c handles codes [c*64, c*64+64)  (verified R4-R9) ----
__global__ __launch_bounds__(256)
void vq_prep(const float* __restrict__ E, float* __restrict__ ET,
             char* __restrict__ ETbf, float* __restrict__ norms) {
    __shared__ float tile[256][64];   // [k][code_local]
    const int t = threadIdx.x;
    const int c = blockIdx.x;

    #pragma unroll
    for (int i = 0; i < 16; ++i) {
        const int k = i * 16 + (t >> 4);
        *(float4*)&tile[k][(t & 15) * 4] =
            *(const float4*)&E[(size_t)k * Kcode + c * 64 + (t & 15) * 4];
    }
    __syncthreads();

    if (t < 64) {
        float s = 0.f;
        for (int k = 0; k < 256; ++k) s = fmaf(tile[k][t], tile[k][t], s);
        norms[c * 64 + t] = s;
    }
    #pragma unroll
    for (int j = 0; j < 16; ++j) {
        const int cl = t >> 2, k0 = (t & 3) * 64 + j * 4;
        float4 v = {tile[k0][cl], tile[k0 + 1][cl], tile[k0 + 2][cl], tile[k0 + 3][cl]};
        *(float4*)&ET[(size_t)(c * 64 + cl) * Ddim + k0] = v;
    }
    // ETbf fragment-linear: group G (16 codes) at byte G*8192 + s*1024 + l*16;
    // lane l: code = G*16 + (l&15), k = s*32 + (l>>4)*8 .. +8
    #pragma unroll
    for (int i = 0; i < 8; ++i) {
        const int wd = i * 256 + t;
        const int g = wd >> 9, s = (wd >> 6) & 7, l = wd & 63;
        const int cl = g * 16 + (l & 15);
        const int k0 = s * 32 + (l >> 4) * 8;
        union { uint4 v; ushort_t u[8]; } pk;
        #pragma unroll
        for (int j = 0; j < 8; ++j) pk.u[j] = f2bf(tile[k0 + j][cl]);
        *(uint4*)(ETbf + (size_t)c * 32768 + (size_t)wd * 16) = pk.v;
    }
}

// ---- score: 64 rows x 512 codes per block (dim3(2,512) -> 4 blocks/CU) ----
__global__ __launch_bounds__(256, 4)
void vq_score(const float* __restrict__ X, const char* __restrict__ ETbf,
              const float* __restrict__ norms,
              float* __restrict__ rowminG, int* __restrict__ cntG,
              unsigned* __restrict__ escG, u64* __restrict__ candG) {
    __shared__ __align__(16) char smB[2][16384];   // 32 codes x 256 dims bf16
    __shared__ float    nrmS[512];
    __shared__ float    rowminS[64];
    __shared__ int      cntS[64];
    __shared__ unsigned escS[64];
    __shared__ u64      candS[64][CAPG];

    const int t = threadIdx.x;
    const int l = t & 63;
    const int w = t >> 6;
    const int l15 = l & 15, lq = l >> 4;
    const int split = blockIdx.x;            // 0/1
    const int row0blk = blockIdx.y * 64;

    if (t < 64) { cntS[t] = 0; escS[t] = 0; }
    #pragma unroll
    for (int i = 0; i < 2; ++i)
        nrmS[i * 256 + t] = norms[split * 512 + i * 256 + t];

    // ---- A fragments: wave w owns rows [row0blk + w*16, +16)  (32 VGPRs) --
    bf16x8 afrag[8];
    #pragma unroll
    for (int s = 0; s < 8; ++s) {
        const float* xp = X + (size_t)(row0blk + w * 16 + l15) * Ddim
                          + s * 32 + lq * 8;
        const float4 v0 = *(const float4*)xp;
        const float4 v1 = *(const float4*)(xp + 4);
        union { bf16x8 v; ushort_t u[8]; } pk;
        pk.u[0] = f2bf(v0.x); pk.u[1] = f2bf(v0.y);
        pk.u[2] = f2bf(v0.z); pk.u[3] = f2bf(v0.w);
        pk.u[4] = f2bf(v1.x); pk.u[5] = f2bf(v1.y);
        pk.u[6] = f2bf(v1.z); pk.u[7] = f2bf(v1.w);
        afrag[s] = pk.v;
    }

    // per-lane top-3 tracking (values; indices only for top-2)
    float b1v[4], b2v[4], b3v[4];
    int   b1i[4], b2i[4];
    #pragma unroll
    for (int r = 0; r < 4; ++r) {
        b1v[r] = 3.4e38f; b2v[r] = 3.4e38f; b3v[r] = 3.4e38f;
        b1i[r] = 0; b2i[r] = 0;
    }

    auto STAGE = [&](int c, int buf) {
        const char* src = ETbf + ((size_t)(split * 16 + c) << 14);
        #pragma unroll
        for (int i = 0; i < 4; ++i)
            gload_lds16(src + (size_t)((i * 256 + t) << 4),
                        smB[buf] + ((i * 256 + (t & ~63)) << 4));
    };

    auto COMPUTE = [&](int c, int buf) {
        #pragma unroll
        for (int g = 0; g < 2; ++g) {
            const char* base = smB[buf] + ((g * 8) * 64 + l) * 16;
            bf16x8 b[8];
            #pragma unroll
            for (int s = 0; s < 8; ++s) b[s] = *(const bf16x8*)(base + s * 1024);
            f32x4 a0 = {0.f, 0.f, 0.f, 0.f}, a1 = {0.f, 0.f, 0.f, 0.f};
            #pragma unroll
            for (int s = 0; s < 8; s += 2) {     // two independent chains
                a0 = __builtin_amdgcn_mfma_f32_16x16x32_bf16(afrag[s], b[s], a0, 0, 0, 0);
                a1 = __builtin_amdgcn_mfma_f32_16x16x32_bf16(afrag[s + 1], b[s + 1], a1, 0, 0, 0);
            }
            const int cloc = c * 32 + g * 16 + l15;
            const float nk = nrmS[cloc];
            const int code = split * 512 + cloc;
            #pragma unroll
            for (int r = 0; r < 4; ++r) {
                const float sc = fmaf(-2.f, a0[r] + a1[r], nk);
                if (sc < b1v[r]) {
                    b3v[r] = b2v[r]; b2v[r] = b1v[r]; b2i[r] = b1i[r];
                    b1v[r] = sc; b1i[r] = code;
                } else if (sc < b2v[r]) {
                    b3v[r] = b2v[r]; b2v[r] = sc; b2i[r] = code;
                } else if (sc < b3v[r]) {
                    b3v[r] = sc;
                }
            }
        }
    };

    // ---- chunk pipeline: 16 chunks of 32 codes (R7-proven loop) ----
    STAGE(0, 0);
    __syncthreads();
    for (int c = 0; c < 16; ++c) {
        if (c < 15) STAGE(c + 1, (c + 1) & 1);
        COMPUTE(c, c & 1);
        __syncthreads();
    }

    // ---- emission: split-local threshold; push b1/b2, escalate on b3 ----
    #pragma unroll
    for (int r = 0; r < 4; ++r) {
        float m = b1v[r];
        #pragma unroll
        for (int off = 1; off < 16; off <<= 1)
            m = fminf(m, __shfl_xor(m, off, 16));
        const int rowL = w * 16 + lq * 4 + r;
        if (l15 == 0) rowminS[rowL] = m;
        const float thr = m + MARGIN;
        if (b1v[r] <= thr) {
            const int p = atomicAdd(&cntS[rowL], 1);
            if (p < CAPG) candS[rowL][p] = packKey(b1v[r], b1i[r]);
        }
        if (b2v[r] <= thr) {
            const int p = atomicAdd(&cntS[rowL], 1);
            if (p < CAPG) candS[rowL][p] = packKey(b2v[r], b2i[r]);
        }
        if (b3v[r] <= thr)
            atomicOr(&escS[rowL], 1u << l15);   // lane may have dropped a 4th+
    }
    __syncthreads();

    // ---- write block meta ----
    const size_t gbase = (size_t)split * Mrows + row0blk;
    if (t < 64) {
        rowminG[gbase + t] = rowminS[t];
        cntG[gbase + t]    = cntS[t];
        escG[gbase + t]    = escS[t];
    }
    for (int e = t; e < 64 * CAPG; e += 256) {
        const int rr = e / CAPG, j = e % CAPG;
        const int n = cntS[rr] < CAPG ? cntS[rr] : CAPG;
        candG[(gbase + rr) * CAPG + j] = (j < n) ? candS[rr][j] : ~0ULL;
    }
}

// ---- merge: all paths lane-parallel / bounded (no stragglers) ----
__global__ __launch_bounds__(256)
void vq_merge(const float* __restrict__ X, const float* __restrict__ ET,
              const float* __restrict__ norms,
              const float* __restrict__ rowminG, const int* __restrict__ cntG,
              const unsigned* __restrict__ escG, const u64* __restrict__ candG,
              float* __restrict__ out, double* __restrict__ partials) {
    __shared__ double lred[4];
    const int t = threadIdx.x;
    const int l = t & 63, w = t >> 6;
    double lacc = 0.0;

    for (int rr = 0; rr < 4; ++rr) {
        const int row = blockIdx.x * 16 + w * 4 + rr;
        const float4 x4 = *(const float4*)&X[(size_t)row * Ddim + l * 4];
        const float thr = fminf(rowminG[row], rowminG[Mrows + row]) + MARGIN;
        const int n0 = cntG[row],  n1 = cntG[Mrows + row];
        const unsigned e0 = escG[row], e1 = escG[Mrows + row];

        // shuffle-parallel exact fp32 rescore (one code, all 64 lanes)
        auto rescoreS = [&](int code) -> float {
            const float4 e4 = *(const float4*)&ET[(size_t)code * Ddim + l * 4];
            float d = x4.x * e4.x;
            d = fmaf(x4.y, e4.y, d);
            d = fmaf(x4.z, e4.z, d);
            d = fmaf(x4.w, e4.w, d);
            #pragma unroll
            for (int off = 1; off < 64; off <<= 1) d += __shfl_xor(d, off, 64);
            return norms[code] - 2.f * d;
        };
        // per-lane serial exact fp32 score (lane-parallel over codes)
        auto laneDot = [&](int cd) -> float {
            const float* ep = ET + (size_t)cd * Ddim;
            const float* xp = X + (size_t)row * Ddim;
            float s0 = 0.f, s1 = 0.f, s2 = 0.f, s3 = 0.f;
            for (int d0 = 0; d0 < 64; ++d0) {
                const float4 e4 = *(const float4*)(ep + d0 * 4);
                const float4 xx = *(const float4*)(xp + d0 * 4);
                s0 = fmaf(xx.x, e4.x, s0); s1 = fmaf(xx.y, e4.y, s1);
                s2 = fmaf(xx.z, e4.z, s2); s3 = fmaf(xx.w, e4.w, s3);
            }
            return norms[cd] - 2.f * ((s0 + s1) + (s2 + s3));
        };

        int code;
        if (n0 > CAPG || n1 > CAPG) {
            // stored list incomplete (statistically never): lane-parallel
            // full 1024-code fp32 scan, 16 codes/lane
            u64 k = ~0ULL;
            for (int i = 0; i < 16; ++i) {
                const int cd = i * 64 + l;
                const u64 k2 = packKey(laneDot(cd), cd);
                if (k2 < k) k = k2;
            }
            #pragma unroll
            for (int off = 1; off < 64; off <<= 1) {
                const u64 o = __shfl_xor(k, off, 64);
                if (o < k) k = o;
            }
            code = (int)(k & 0xffffffffu);
        } else {
            int kept = 0, only = -1;
            for (int sp = 0; sp < 2; ++sp) {
                const int n = sp ? n1 : n0;
                const u64* cl = candG + ((size_t)sp * Mrows + row) * CAPG;
                for (int j = 0; j < n; ++j) {
                    const u64 key = cl[j];
                    if (unpackScore(key) <= thr) { only = (int)(key & 0xffffffffu); ++kept; }
                }
            }
            if (kept == 1 && e0 == 0 && e1 == 0) {
                code = only;    // provably the argmin
            } else {
                float bS = 3.4e38f; int bC = 0x7fffffff;
                for (int sp = 0; sp < 2; ++sp) {
                    const int n = sp ? n1 : n0;
                    const u64* cl = candG + ((size_t)sp * Mrows + row) * CAPG;
                    for (int j = 0; j < n; ++j) {
                        const u64 key = cl[j];
                        if (unpackScore(key) > thr) continue;
                        const int cd = (int)(key & 0xffffffffu);
                        const float s = rescoreS(cd);
                        if (s < bS || (s == bS && cd < bC)) { bS = s; bC = cd; }
                    }
                    unsigned m2 = sp ? e1 : e0;
                    while (m2) {   // esc lane: 32 codes, lane-parallel
                        const int c15 = __ffs(m2) - 1; m2 &= m2 - 1;
                        u64 k = ~0ULL;
                        if (l < 32) {
                            const int cd = sp * 512 + l * 16 + c15;
                            k = packKey(laneDot(cd), cd);
                        }
                        #pragma unroll
                        for (int off = 1; off < 64; off <<= 1) {
                            const u64 o = __shfl_xor(k, off, 64);
                            if (o < k) k = o;
                        }
                        const float s = unpackScore(k);
                        const int cd2 = (int)(k & 0xffffffffu);
                        if (s < bS || (s == bS && cd2 < bC)) { bS = s; bC = cd2; }
                    }
                }
                code = bC;
            }
        }

        const float4 q4 = *(const float4*)&ET[(size_t)code * Ddim + l * 4];
        *(float4*)&out[(size_t)row * Ddim + l * 4] = q4;
        const double dx = (double)(q4.x - x4.x), dy = (double)(q4.y - x4.y);
        const double dz = (double)(q4.z - x4.z), dw = (double)(q4.w - x4.w);
        lacc += dx * dx + dy * dy + dz * dz + dw * dw;
    }
    #pragma unroll
    for (int off = 32; off; off >>= 1) lacc += __shfl_down(lacc, off, 64);
    if (l == 0) lred[w] = lacc;
    __syncthreads();
    if (t == 0)
        partials[blockIdx.x] = lred[0] + lred[1] + lred[2] + lred[3];
}

// ---- final loss ----
__global__ __launch_bounds__(256)
void vq_lossk(const double* __restrict__ partials, float* __restrict__ lossOut) {
    __shared__ double red[4];
    double v = 0.0;
    for (int i = threadIdx.x; i < 2048; i += 256) v += partials[i];
    #pragma unroll
    for (int off = 32; off; off >>= 1) v += __shfl_down(v, off, 64);
    const int lane = threadIdx.x & 63, grp = threadIdx.x >> 6;
    if (lane == 0) red[grp] = v;
    __syncthreads();
    if (threadIdx.x == 0)
        lossOut[0] = (float)(1.25 * (red[0] + red[1] + red[2] + red[3]) /
                             (double)((size_t)Mrows * Ddim));
}

// ===========================================================================
extern "C" void kernel_launch(void* const* d_in, const int* in_sizes, int n_in,
                              void* d_out, int out_size, void* d_ws, size_t ws_size,
                              hipStream_t stream) {
    const float* X = (const float*)d_in[0];
    const float* E = (const float*)d_in[1];
    float* out = (float*)d_out;
    char* ws = (char*)d_ws;

    // workspace: candG 4MB | partials 16KB | ET 1MB | ETbf 512KB |
    //            norms 4KB | rowminG 256KB | cntG 256KB | escG 256KB
    const size_t candB = (size_t)2 * Mrows * CAPG * 8;
    const size_t partB = 2048 * 8;
    const size_t etB   = (size_t)Kcode * Ddim * 4;
    const size_t etbfB = (size_t)Kcode * Ddim * 2;
    const size_t nrmB  = (size_t)Kcode * 4;
    const size_t rmB   = (size_t)2 * Mrows * 4;
    char* p = ws;
    u64*      candG    = (u64*)p;      p += candB;
    double*   partials = (double*)p;   p += partB;
    float*    ET       = (float*)p;    p += etB;
    char*     ETbf     = p;            p += etbfB;
    float*    norms    = (float*)p;    p += nrmB;
    float*    rowminG  = (float*)p;    p += rmB;
    int*      cntG     = (int*)p;      p += rmB;
    unsigned* escG     = (unsigned*)p;

    vq_prep<<<16, 256, 0, stream>>>(E, ET, ETbf, norms);
    vq_score<<<dim3(2, Mrows / 64), 256, 0, stream>>>(X, ETbf, norms,
                                                      rowminG, cntG, escG, candG);
    vq_merge<<<Mrows / 16, 256, 0, stream>>>(X, ET, norms, rowminG, cntG, escG,
                                             candG, out, partials);
    vq_lossk<<<1, 256, 0, stream>>>(partials, out + (size_t)Mrows * Ddim);
}